// Round 1
// baseline (3006.338 us; speedup 1.0000x reference)
//
#include <hip/hip_runtime.h>

// Problem constants (fixed by reference).
constexpr int NNODES = 200000;
constexpr int NAUT   = 100000;
constexpr int NEDGE  = 600000;
constexpr int HIDC   = 128;
constexpr int OUTCH  = 64;
constexpr int RELS   = 4;
constexpr int SCAN_N = RELS * NNODES;  // 800000 bins
constexpr int LDA    = HIDC + 4;       // LDS pad: breaks row-aligned bank conflicts

// ---------------- prep kernels ----------------

// W[r][i][o] = sum_b comp[r][b] * basis[b][i][o]
__global__ void makew_kernel(const float* __restrict__ basis, const float* __restrict__ comp,
                             float* __restrict__ W, int io_sz) {
    int idx = blockIdx.x * 256 + threadIdx.x;
    if (idx >= RELS * io_sz) return;
    int r = idx / io_sz, io = idx % io_sz;
    float s = 0.f;
#pragma unroll
    for (int b = 0; b < 4; b++) s += comp[r * 4 + b] * basis[b * io_sz + io];
    W[idx] = s;
}

// int count per (relation, dst) bin
__global__ void count_kernel(const int* __restrict__ dst, const int* __restrict__ et,
                             int* __restrict__ bins) {
    int e = blockIdx.x * 256 + threadIdx.x;
    if (e < NEDGE) atomicAdd(&bins[et[e] * NNODES + dst[e]], 1);
}

// ---- 3-phase exclusive scan over 800k bins, in-place (counts -> starts) ----
__global__ void scan1_kernel(int* __restrict__ bins, int* __restrict__ blockSums) {
    __shared__ int s[256];
    int b = blockIdx.x, t = threadIdx.x;
    int base = b * 1024 + t * 4;
    int v[4], sum = 0;
#pragma unroll
    for (int i = 0; i < 4; i++) {
        v[i] = (base + i < SCAN_N) ? bins[base + i] : 0;
        sum += v[i];
    }
    s[t] = sum;
    __syncthreads();
    for (int off = 1; off < 256; off <<= 1) {
        int x = (t >= off) ? s[t - off] : 0;
        __syncthreads();
        if (t >= off) s[t] += x;
        __syncthreads();
    }
    int run = s[t] - sum;  // exclusive prefix of this thread's chunk
    if (t == 255) blockSums[b] = s[255];
#pragma unroll
    for (int i = 0; i < 4; i++) {
        if (base + i < SCAN_N) bins[base + i] = run;
        run += v[i];
    }
}

__global__ void scan2_kernel(int* __restrict__ blockSums, int nb) {
    __shared__ int s[256];
    int t = threadIdx.x;
    int carry = 0;
    for (int base = 0; base < nb; base += 256) {
        int v = (base + t < nb) ? blockSums[base + t] : 0;
        s[t] = v;
        __syncthreads();
        for (int off = 1; off < 256; off <<= 1) {
            int x = (t >= off) ? s[t - off] : 0;
            __syncthreads();
            if (t >= off) s[t] += x;
            __syncthreads();
        }
        if (base + t < nb) blockSums[base + t] = carry + (s[t] - v);
        int total = s[255];
        __syncthreads();
        carry += total;
    }
}

// add block carries; also produce the scatter-cursor copy
__global__ void scan3_kernel(int* __restrict__ bins, const int* __restrict__ blockSums,
                             int* __restrict__ binCur) {
    int i = blockIdx.x * 256 + threadIdx.x;
    if (i < SCAN_N) {
        int v = bins[i] + blockSums[i >> 10];
        bins[i] = v;
        binCur[i] = v;
    }
}

// scatter SRC ids into (relation,dst)-sorted order; binCur becomes end-offsets
__global__ void scatter_kernel(const int* __restrict__ src, const int* __restrict__ dst,
                               const int* __restrict__ et, int* __restrict__ binCur,
                               int* __restrict__ srcSorted) {
    int e = blockIdx.x * 256 + threadIdx.x;
    if (e < NEDGE) {
        int bin = et[e] * NNODES + dst[e];
        int pos = atomicAdd(&binCur[bin], 1);
        srcSorted[pos] = src[e];
    }
}

// ---------------- projection GEMM: C[M,128] = relu(A[M,K] @ B[K,128] + bias) ----
__global__ __launch_bounds__(256) void gemm_kernel(const float* __restrict__ A,
                                                   const float* __restrict__ B,
                                                   const float* __restrict__ bias,
                                                   float* __restrict__ C, int M, int K) {
    __shared__ float sA[64 * 128];
    int tid = threadIdx.x;
    int row0 = blockIdx.x * 64;

    for (int i = tid; i < (64 * K) >> 2; i += 256) {
        int off = i << 2;
        int rr = off / K, cc = off % K;
        int row = row0 + rr;
        float4 v = {0.f, 0.f, 0.f, 0.f};
        if (row < M) v = *(const float4*)(A + (long)row * K + cc);
        *(float4*)(sA + rr * K + cc) = v;
    }
    __syncthreads();

    int cg = tid & 31, rg = tid >> 5;
    int c0 = cg * 4, r0 = rg * 8;
    float acc[8][4];
#pragma unroll
    for (int i = 0; i < 8; i++)
#pragma unroll
        for (int j = 0; j < 4; j++) acc[i][j] = 0.f;

#pragma unroll 2
    for (int k = 0; k < K; k += 4) {
        float a[8][4];
#pragma unroll
        for (int i = 0; i < 8; i++)
            *(float4*)(a[i]) = *(const float4*)(sA + (r0 + i) * K + k);
#pragma unroll
        for (int j = 0; j < 4; j++) {
            float b[4];
            *(float4*)b = *(const float4*)(B + (k + j) * 128 + c0);
#pragma unroll
            for (int i = 0; i < 8; i++)
#pragma unroll
                for (int jj = 0; jj < 4; jj++)
                    acc[i][jj] = fmaf(a[i][j], b[jj], acc[i][jj]);
        }
    }

#pragma unroll
    for (int i = 0; i < 8; i++) {
        int row = row0 + r0 + i;
        if (row >= M) continue;
        float v[4];
#pragma unroll
        for (int jj = 0; jj < 4; jj++) v[jj] = fmaxf(acc[i][jj] + bias[c0 + jj], 0.f);
        *(float4*)(C + (long)row * 128 + c0) = *(float4*)v;
    }
}

// ---------------- fused dst-centric RGCN conv (NO atomics) ----------------
// Producer/consumer wave specialization with double-buffered LDS:
//   - 512 threads. Waves 4-7 (producers) gather relation ph+1's per-dst mean
//     into sA[(ph+1)&1] while waves 0-3 (consumers) run the register-blocked
//     GEMM of phase ph from sA[ph&1] against W[ph] (L2-resident).
//   - Phase time becomes max(gather, gemm) instead of sum: the gather is a
//     latency-bound pointer-chase that previously left VALU at 47%.
//   - LDS 2*33792B = 67.6KB -> 2 blocks/CU = 16 waves/CU.

__device__ __forceinline__ void gather_phase(const float* __restrict__ x,
                                             const int* __restrict__ binStart,
                                             const int* __restrict__ binEnd,
                                             const int* __restrict__ srcSorted,
                                             float* __restrict__ buf,
                                             int bin, int grow, int gq) {
    int s = binStart[bin], e = binEnd[bin];
    float4 a4[8];
#pragma unroll
    for (int i = 0; i < 8; i++) a4[i] = make_float4(0.f, 0.f, 0.f, 0.f);
    for (int j = s; j < e; j++) {
        const float* xs = x + (long)srcSorted[j] * HIDC;
#pragma unroll
        for (int i = 0; i < 8; i++) {
            float4 v = *(const float4*)(xs + (gq + i * 4) * 4);
            a4[i].x += v.x; a4[i].y += v.y; a4[i].z += v.z; a4[i].w += v.w;
        }
    }
    float sc = 1.0f / (float)max(e - s, 1);
#pragma unroll
    for (int i = 0; i < 8; i++) {
        float4 w = a4[i];
        w.x *= sc; w.y *= sc; w.z *= sc; w.w *= sc;
        *(float4*)(buf + grow * LDA + (gq + i * 4) * 4) = w;
    }
}

template <int NC, bool HASROOT, bool DORELU>
__global__ __launch_bounds__(512, 4) void conv_kernel(const float* __restrict__ x,
                                                      const float* __restrict__ Wall,
                                                      const float* __restrict__ root,
                                                      const int* __restrict__ binStart,
                                                      const int* __restrict__ binEnd,
                                                      const int* __restrict__ srcSorted,
                                                      float* __restrict__ out) {
    constexpr int NCT = NC / 32;
    __shared__ float sA[2][64 * LDA];
    int tid = threadIdx.x;
    int v0 = blockIdx.x * 64;
    const bool isProd = tid >= 256;
    const int ptid = tid & 255;

    // consumer tile coords
    const int cg = ptid & 31, rg = ptid >> 5;
    const int c0 = cg * NCT, r0 = rg * 8;
    // producer coords: 4 threads per dst row, interleaved column slices
    const int grow = ptid >> 2, gq = ptid & 3;

    float acc[8][NCT];
#pragma unroll
    for (int i = 0; i < 8; i++)
#pragma unroll
        for (int j = 0; j < NCT; j++) acc[i][j] = 0.f;

    constexpr int NPHASE = HASROOT ? RELS + 1 : RELS;

    // prologue: producers fill buffer 0 with relation 0
    if (isProd) {
        gather_phase(x, binStart, binEnd, srcSorted, sA[0],
                     0 * NNODES + v0 + grow, grow, gq);
    }
    __syncthreads();

#pragma unroll 1
    for (int ph = 0; ph < NPHASE; ph++) {
        if (isProd) {
            int pn = ph + 1;
            if (pn < NPHASE) {
                float* buf = sA[pn & 1];
                if (pn < RELS) {
                    gather_phase(x, binStart, binEnd, srcSorted, buf,
                                 pn * NNODES + v0 + grow, grow, gq);
                } else {
                    // root phase: coalesced load of the block's own 64 x-rows
#pragma unroll
                    for (int i = 0; i < 8; i++) {
                        int i4 = ptid + 256 * i;  // 2048 float4 = 64x128 floats
                        int row = i4 >> 5, col4 = i4 & 31;
                        *(float4*)(buf + row * LDA + col4 * 4) =
                            *(const float4*)(x + (long)(v0 + row) * HIDC + col4 * 4);
                    }
                }
            }
        } else {
            const float* __restrict__ B = (ph < RELS) ? (Wall + ph * HIDC * NC) : root;
            const float* __restrict__ sbuf = sA[ph & 1];
#pragma unroll 2
            for (int k = 0; k < HIDC; k += 4) {
                float a[8][4];
#pragma unroll
                for (int i = 0; i < 8; i++)
                    *(float4*)(a[i]) = *(const float4*)(sbuf + (r0 + i) * LDA + k);
#pragma unroll
                for (int j = 0; j < 4; j++) {
                    float b[NCT];
                    if constexpr (NCT == 4)
                        *(float4*)b = *(const float4*)(B + (k + j) * NC + c0);
                    else
                        *(float2*)b = *(const float2*)(B + (k + j) * NC + c0);
#pragma unroll
                    for (int i = 0; i < 8; i++)
#pragma unroll
                        for (int jj = 0; jj < NCT; jj++)
                            acc[i][jj] = fmaf(a[i][j], b[jj], acc[i][jj]);
                }
            }
        }
        __syncthreads();
    }

    // epilogue (consumers): exactly one coalesced store per output element
    if (!isProd) {
#pragma unroll
        for (int i = 0; i < 8; i++) {
            int row = v0 + r0 + i;  // NNODES % 64 == 0: no guard needed
            float v[NCT];
#pragma unroll
            for (int jj = 0; jj < NCT; jj++)
                v[jj] = DORELU ? fmaxf(acc[i][jj], 0.f) : acc[i][jj];
            if constexpr (NCT == 4)
                *(float4*)(out + (long)row * NC + c0) = *(float4*)v;
            else
                *(float2*)(out + (long)row * NC + c0) = *(float2*)v;
        }
    }
}

// ---------------- launch ----------------

extern "C" void kernel_launch(void* const* d_in, const int* in_sizes, int n_in,
                              void* d_out, int out_size, void* d_ws, size_t ws_size,
                              hipStream_t stream) {
    const float* xa     = (const float*)d_in[0];
    const float* xp     = (const float*)d_in[1];
    const int*   src    = (const int*)d_in[2];
    const int*   dst    = (const int*)d_in[3];
    const int*   et     = (const int*)d_in[4];
    const float* Wpa    = (const float*)d_in[5];
    const float* bpa    = (const float*)d_in[6];
    const float* Wpb    = (const float*)d_in[7];
    const float* bpb    = (const float*)d_in[8];
    const float* basis0 = (const float*)d_in[9];
    const float* comp0  = (const float*)d_in[10];
    const float* basis1 = (const float*)d_in[11];
    const float* comp1  = (const float*)d_in[12];
    const float* root1  = (const float*)d_in[13];
    const float* basis2 = (const float*)d_in[14];
    const float* comp2  = (const float*)d_in[15];
    const float* root2  = (const float*)d_in[16];

    // d_out layout: final [N,64] | x_lat0 [N,128] | x_lat1 [N,128] | x_lat2 [N,128]
    float* out_final = (float*)d_out;
    float* x0 = out_final + (size_t)NNODES * OUTCH;
    float* x1 = x0 + (size_t)NNODES * HIDC;
    float* x2 = x1 + (size_t)NNODES * HIDC;

    // workspace (~9.3 MB)
    float* W0      = (float*)d_ws;                      // 4*128*128
    float* W1      = W0 + RELS * HIDC * HIDC;           // 4*128*128
    float* W2      = W1 + RELS * HIDC * HIDC;           // 4*128*64
    int* bins      = (int*)(W2 + RELS * HIDC * OUTCH);  // 800000: counts -> starts
    int* binCur    = bins + SCAN_N;                     // 800000: cursor -> ends
    int* blockSums = binCur + SCAN_N;                   // 800
    int* srcSorted = blockSums + 800;                   // 600000

    dim3 b256(256);
    dim3 b512(512);
    int egrid = (NEDGE + 255) / 256;
    int nScanBlocks = (SCAN_N + 1023) / 1024;  // 782

    // ---- counting-sort of src ids by (relation, dst) ----
    hipMemsetAsync(bins, 0, (size_t)SCAN_N * sizeof(int), stream);
    hipLaunchKernelGGL(count_kernel, dim3(egrid), b256, 0, stream, dst, et, bins);
    hipLaunchKernelGGL(scan1_kernel, dim3(nScanBlocks), b256, 0, stream, bins, blockSums);
    hipLaunchKernelGGL(scan2_kernel, dim3(1), b256, 0, stream, blockSums, nScanBlocks);
    hipLaunchKernelGGL(scan3_kernel, dim3((SCAN_N + 255) / 256), b256, 0, stream,
                       bins, blockSums, binCur);
    hipLaunchKernelGGL(scatter_kernel, dim3(egrid), b256, 0, stream,
                       src, dst, et, binCur, srcSorted);

    // ---- materialize relation weights ----
    hipLaunchKernelGGL(makew_kernel, dim3((RELS * HIDC * HIDC + 255) / 256), b256, 0, stream,
                       basis0, comp0, W0, HIDC * HIDC);
    hipLaunchKernelGGL(makew_kernel, dim3((RELS * HIDC * HIDC + 255) / 256), b256, 0, stream,
                       basis1, comp1, W1, HIDC * HIDC);
    hipLaunchKernelGGL(makew_kernel, dim3((RELS * HIDC * OUTCH + 255) / 256), b256, 0, stream,
                       basis2, comp2, W2, HIDC * OUTCH);

    // ---- projections -> x_lat0 ----
    hipLaunchKernelGGL(gemm_kernel, dim3((NAUT + 63) / 64), b256, 0, stream,
                       xa, Wpa, bpa, x0, NAUT, 64);
    hipLaunchKernelGGL(gemm_kernel, dim3((NAUT + 63) / 64), b256, 0, stream,
                       xp, Wpb, bpb, x0 + (size_t)NAUT * HIDC, NAUT, 96);

    int cgrid = NNODES / 64;  // 3125, exact

    // conv0: x1 = relu(aggr(x0))            (no root)
    hipLaunchKernelGGL((conv_kernel<128, false, true>), dim3(cgrid), b512, 0, stream,
                       x0, W0, (const float*)nullptr, bins, binCur, srcSorted, x1);
    // conv1: x2 = relu(x1 @ root1 + aggr(x1))
    hipLaunchKernelGGL((conv_kernel<128, true, true>), dim3(cgrid), b512, 0, stream,
                       x1, W1, root1, bins, binCur, srcSorted, x2);
    // conv2: final = x2 @ root2 + aggr(x2)  (no relu)
    hipLaunchKernelGGL((conv_kernel<64, true, false>), dim3(cgrid), b512, 0, stream,
                       x2, W2, root2, bins, binCur, srcSorted, out_final);
}

// Round 2
// 2137.438 us; speedup vs baseline: 1.4065x; 1.4065x over previous
//
#include <hip/hip_runtime.h>

// Problem constants (fixed by reference).
constexpr int NNODES = 200000;
constexpr int NAUT   = 100000;
constexpr int NEDGE  = 600000;
constexpr int HIDC   = 128;
constexpr int OUTCH  = 64;
constexpr int RELS   = 4;
constexpr int SCAN_N = RELS * NNODES;  // 800000 bins
constexpr int LDA    = HIDC + 4;       // LDS pad: breaks row-aligned bank conflicts

// ---------------- prep kernels ----------------

// W[r][i][o] = sum_b comp[r][b] * basis[b][i][o]
__global__ void makew_kernel(const float* __restrict__ basis, const float* __restrict__ comp,
                             float* __restrict__ W, int io_sz) {
    int idx = blockIdx.x * 256 + threadIdx.x;
    if (idx >= RELS * io_sz) return;
    int r = idx / io_sz, io = idx % io_sz;
    float s = 0.f;
#pragma unroll
    for (int b = 0; b < 4; b++) s += comp[r * 4 + b] * basis[b * io_sz + io];
    W[idx] = s;
}

// int count per (relation, dst) bin
__global__ void count_kernel(const int* __restrict__ dst, const int* __restrict__ et,
                             int* __restrict__ bins) {
    int e = blockIdx.x * 256 + threadIdx.x;
    if (e < NEDGE) atomicAdd(&bins[et[e] * NNODES + dst[e]], 1);
}

// ---- 3-phase exclusive scan over 800k bins, in-place (counts -> starts) ----
__global__ void scan1_kernel(int* __restrict__ bins, int* __restrict__ blockSums) {
    __shared__ int s[256];
    int b = blockIdx.x, t = threadIdx.x;
    int base = b * 1024 + t * 4;
    int v[4], sum = 0;
#pragma unroll
    for (int i = 0; i < 4; i++) {
        v[i] = (base + i < SCAN_N) ? bins[base + i] : 0;
        sum += v[i];
    }
    s[t] = sum;
    __syncthreads();
    for (int off = 1; off < 256; off <<= 1) {
        int x = (t >= off) ? s[t - off] : 0;
        __syncthreads();
        if (t >= off) s[t] += x;
        __syncthreads();
    }
    int run = s[t] - sum;  // exclusive prefix of this thread's chunk
    if (t == 255) blockSums[b] = s[255];
#pragma unroll
    for (int i = 0; i < 4; i++) {
        if (base + i < SCAN_N) bins[base + i] = run;
        run += v[i];
    }
}

__global__ void scan2_kernel(int* __restrict__ blockSums, int nb) {
    __shared__ int s[256];
    int t = threadIdx.x;
    int carry = 0;
    for (int base = 0; base < nb; base += 256) {
        int v = (base + t < nb) ? blockSums[base + t] : 0;
        s[t] = v;
        __syncthreads();
        for (int off = 1; off < 256; off <<= 1) {
            int x = (t >= off) ? s[t - off] : 0;
            __syncthreads();
            if (t >= off) s[t] += x;
            __syncthreads();
        }
        if (base + t < nb) blockSums[base + t] = carry + (s[t] - v);
        int total = s[255];
        __syncthreads();
        carry += total;
    }
}

// add block carries; also produce the scatter-cursor copy
__global__ void scan3_kernel(int* __restrict__ bins, const int* __restrict__ blockSums,
                             int* __restrict__ binCur) {
    int i = blockIdx.x * 256 + threadIdx.x;
    if (i < SCAN_N) {
        int v = bins[i] + blockSums[i >> 10];
        bins[i] = v;
        binCur[i] = v;
    }
}

// scatter SRC ids into (relation,dst)-sorted order; binCur becomes end-offsets
__global__ void scatter_kernel(const int* __restrict__ src, const int* __restrict__ dst,
                               const int* __restrict__ et, int* __restrict__ binCur,
                               int* __restrict__ srcSorted) {
    int e = blockIdx.x * 256 + threadIdx.x;
    if (e < NEDGE) {
        int bin = et[e] * NNODES + dst[e];
        int pos = atomicAdd(&binCur[bin], 1);
        srcSorted[pos] = src[e];
    }
}

// ---------------- projection GEMM: C[M,128] = relu(A[M,K] @ B[K,128] + bias) ----
__global__ __launch_bounds__(256) void gemm_kernel(const float* __restrict__ A,
                                                   const float* __restrict__ B,
                                                   const float* __restrict__ bias,
                                                   float* __restrict__ C, int M, int K) {
    __shared__ float sA[64 * 128];
    int tid = threadIdx.x;
    int row0 = blockIdx.x * 64;

    for (int i = tid; i < (64 * K) >> 2; i += 256) {
        int off = i << 2;
        int rr = off / K, cc = off % K;
        int row = row0 + rr;
        float4 v = {0.f, 0.f, 0.f, 0.f};
        if (row < M) v = *(const float4*)(A + (long)row * K + cc);
        *(float4*)(sA + rr * K + cc) = v;
    }
    __syncthreads();

    int cg = tid & 31, rg = tid >> 5;
    int c0 = cg * 4, r0 = rg * 8;
    float acc[8][4];
#pragma unroll
    for (int i = 0; i < 8; i++)
#pragma unroll
        for (int j = 0; j < 4; j++) acc[i][j] = 0.f;

#pragma unroll 2
    for (int k = 0; k < K; k += 4) {
        float a[8][4];
#pragma unroll
        for (int i = 0; i < 8; i++)
            *(float4*)(a[i]) = *(const float4*)(sA + (r0 + i) * K + k);
#pragma unroll
        for (int j = 0; j < 4; j++) {
            float b[4];
            *(float4*)b = *(const float4*)(B + (k + j) * 128 + c0);
#pragma unroll
            for (int i = 0; i < 8; i++)
#pragma unroll
                for (int jj = 0; jj < 4; jj++)
                    acc[i][jj] = fmaf(a[i][j], b[jj], acc[i][jj]);
        }
    }

#pragma unroll
    for (int i = 0; i < 8; i++) {
        int row = row0 + r0 + i;
        if (row >= M) continue;
        float v[4];
#pragma unroll
        for (int jj = 0; jj < 4; jj++) v[jj] = fmaxf(acc[i][jj] + bias[c0 + jj], 0.f);
        *(float4*)(C + (long)row * 128 + c0) = *(float4*)v;
    }
}

// ---------------- fused dst-centric RGCN conv (NO atomics) ----------------
// Block owns 64 dst rows. Per relation: 4 threads/row sum the row's (sorted,
// contiguous) neighbors into registers, scale by 1/deg, stage to LDS; then a
// register-blocked GEMM vs W[r] (L2-resident) accumulates into C.
//
// GEMM thread tile is RPT rows x 8 cols (was 8x4). LDS-read amplification of
// the A tile is NC/cols_per_thread: 8 cols halves it for NC=128 (and 4x for
// NC=64) vs the 4-col tile. ds_read_b128 port time was the binding resource
// (~250us/conv at 85B/cy/CU vs 167us FMA issue). Register profile unchanged
// (acc = RPT*8 = 32 floats for NC=128), occupancy unchanged (4 blk/CU).
template <int NC, bool HASROOT, bool DORELU>
__global__ __launch_bounds__(256) void conv_kernel(const float* __restrict__ x,
                                                   const float* __restrict__ Wall,
                                                   const float* __restrict__ root,
                                                   const int* __restrict__ binStart,
                                                   const int* __restrict__ binEnd,
                                                   const int* __restrict__ srcSorted,
                                                   float* __restrict__ out) {
    constexpr int NG  = NC / 8;  // column groups: 16 (NC=128) or 8 (NC=64)
    constexpr int RPT = NG / 4;  // rows per thread: 4 (NC=128) or 2 (NC=64)
    __shared__ float sA[64 * LDA];
    int tid = threadIdx.x;
    int v0 = blockIdx.x * 64;

    int grow = tid >> 2;  // gather: 4 threads per row
    int gq = tid & 3;     // this thread's interleaved column slice
    const int cg = tid % NG, rg = tid / NG;
    const int c0 = cg * 8, r0 = rg * RPT;

    float acc[RPT][8];
#pragma unroll
    for (int i = 0; i < RPT; i++)
#pragma unroll
        for (int j = 0; j < 8; j++) acc[i][j] = 0.f;

    constexpr int NPHASE = HASROOT ? RELS + 1 : RELS;
#pragma unroll 1
    for (int ph = 0; ph < NPHASE; ph++) {
        if (ph > 0) __syncthreads();  // protect sA from previous phase's readers
        if (ph < RELS) {
            int bin = ph * NNODES + v0 + grow;
            int s = binStart[bin], e = binEnd[bin];
            float4 a4[8];
#pragma unroll
            for (int i = 0; i < 8; i++) a4[i] = make_float4(0.f, 0.f, 0.f, 0.f);
            for (int j = s; j < e; j++) {
                const float* xs = x + (long)srcSorted[j] * HIDC;
#pragma unroll
                for (int i = 0; i < 8; i++) {
                    float4 v = *(const float4*)(xs + (gq + i * 4) * 4);
                    a4[i].x += v.x; a4[i].y += v.y; a4[i].z += v.z; a4[i].w += v.w;
                }
            }
            float sc = 1.0f / (float)max(e - s, 1);
#pragma unroll
            for (int i = 0; i < 8; i++) {
                float4 w = a4[i];
                w.x *= sc; w.y *= sc; w.z *= sc; w.w *= sc;
                *(float4*)(sA + grow * LDA + (gq + i * 4) * 4) = w;
            }
        } else {
            // root phase: coalesced load of the block's own 64 x-rows
#pragma unroll
            for (int i = 0; i < 8; i++) {
                int i4 = tid + 256 * i;  // 2048 float4 = 64x128 floats
                int row = i4 >> 5, col4 = i4 & 31;
                *(float4*)(sA + row * LDA + col4 * 4) =
                    *(const float4*)(x + (long)(v0 + row) * HIDC + col4 * 4);
            }
        }
        __syncthreads();

        const float* __restrict__ B = (ph < RELS) ? (Wall + ph * HIDC * NC) : root;
#pragma unroll 2
        for (int k = 0; k < HIDC; k += 4) {
            float a[RPT][4];
#pragma unroll
            for (int i = 0; i < RPT; i++)
                *(float4*)(a[i]) = *(const float4*)(sA + (r0 + i) * LDA + k);
#pragma unroll
            for (int j = 0; j < 4; j++) {
                float b[8];
                *(float4*)(b)     = *(const float4*)(B + (k + j) * NC + c0);
                *(float4*)(b + 4) = *(const float4*)(B + (k + j) * NC + c0 + 4);
#pragma unroll
                for (int i = 0; i < RPT; i++)
#pragma unroll
                    for (int jj = 0; jj < 8; jj++)
                        acc[i][jj] = fmaf(a[i][j], b[jj], acc[i][jj]);
            }
        }
    }

    // epilogue: exactly one coalesced store per output element
#pragma unroll
    for (int i = 0; i < RPT; i++) {
        int row = v0 + r0 + i;  // NNODES % 64 == 0: no guard needed
        float v[8];
#pragma unroll
        for (int jj = 0; jj < 8; jj++)
            v[jj] = DORELU ? fmaxf(acc[i][jj], 0.f) : acc[i][jj];
        *(float4*)(out + (long)row * NC + c0)     = *(float4*)(v);
        *(float4*)(out + (long)row * NC + c0 + 4) = *(float4*)(v + 4);
    }
}

// ---------------- launch ----------------

extern "C" void kernel_launch(void* const* d_in, const int* in_sizes, int n_in,
                              void* d_out, int out_size, void* d_ws, size_t ws_size,
                              hipStream_t stream) {
    const float* xa     = (const float*)d_in[0];
    const float* xp     = (const float*)d_in[1];
    const int*   src    = (const int*)d_in[2];
    const int*   dst    = (const int*)d_in[3];
    const int*   et     = (const int*)d_in[4];
    const float* Wpa    = (const float*)d_in[5];
    const float* bpa    = (const float*)d_in[6];
    const float* Wpb    = (const float*)d_in[7];
    const float* bpb    = (const float*)d_in[8];
    const float* basis0 = (const float*)d_in[9];
    const float* comp0  = (const float*)d_in[10];
    const float* basis1 = (const float*)d_in[11];
    const float* comp1  = (const float*)d_in[12];
    const float* root1  = (const float*)d_in[13];
    const float* basis2 = (const float*)d_in[14];
    const float* comp2  = (const float*)d_in[15];
    const float* root2  = (const float*)d_in[16];

    // d_out layout: final [N,64] | x_lat0 [N,128] | x_lat1 [N,128] | x_lat2 [N,128]
    float* out_final = (float*)d_out;
    float* x0 = out_final + (size_t)NNODES * OUTCH;
    float* x1 = x0 + (size_t)NNODES * HIDC;
    float* x2 = x1 + (size_t)NNODES * HIDC;

    // workspace (~9.3 MB)
    float* W0      = (float*)d_ws;                      // 4*128*128
    float* W1      = W0 + RELS * HIDC * HIDC;           // 4*128*128
    float* W2      = W1 + RELS * HIDC * HIDC;           // 4*128*64
    int* bins      = (int*)(W2 + RELS * HIDC * OUTCH);  // 800000: counts -> starts
    int* binCur    = bins + SCAN_N;                     // 800000: cursor -> ends
    int* blockSums = binCur + SCAN_N;                   // 800
    int* srcSorted = blockSums + 800;                   // 600000

    dim3 b256(256);
    int egrid = (NEDGE + 255) / 256;
    int nScanBlocks = (SCAN_N + 1023) / 1024;  // 782

    // ---- counting-sort of src ids by (relation, dst) ----
    hipMemsetAsync(bins, 0, (size_t)SCAN_N * sizeof(int), stream);
    hipLaunchKernelGGL(count_kernel, dim3(egrid), b256, 0, stream, dst, et, bins);
    hipLaunchKernelGGL(scan1_kernel, dim3(nScanBlocks), b256, 0, stream, bins, blockSums);
    hipLaunchKernelGGL(scan2_kernel, dim3(1), b256, 0, stream, blockSums, nScanBlocks);
    hipLaunchKernelGGL(scan3_kernel, dim3((SCAN_N + 255) / 256), b256, 0, stream,
                       bins, blockSums, binCur);
    hipLaunchKernelGGL(scatter_kernel, dim3(egrid), b256, 0, stream,
                       src, dst, et, binCur, srcSorted);

    // ---- materialize relation weights ----
    hipLaunchKernelGGL(makew_kernel, dim3((RELS * HIDC * HIDC + 255) / 256), b256, 0, stream,
                       basis0, comp0, W0, HIDC * HIDC);
    hipLaunchKernelGGL(makew_kernel, dim3((RELS * HIDC * HIDC + 255) / 256), b256, 0, stream,
                       basis1, comp1, W1, HIDC * HIDC);
    hipLaunchKernelGGL(makew_kernel, dim3((RELS * HIDC * OUTCH + 255) / 256), b256, 0, stream,
                       basis2, comp2, W2, HIDC * OUTCH);

    // ---- projections -> x_lat0 ----
    hipLaunchKernelGGL(gemm_kernel, dim3((NAUT + 63) / 64), b256, 0, stream,
                       xa, Wpa, bpa, x0, NAUT, 64);
    hipLaunchKernelGGL(gemm_kernel, dim3((NAUT + 63) / 64), b256, 0, stream,
                       xp, Wpb, bpb, x0 + (size_t)NAUT * HIDC, NAUT, 96);

    int cgrid = NNODES / 64;  // 3125, exact

    // conv0: x1 = relu(aggr(x0))            (no root)
    hipLaunchKernelGGL((conv_kernel<128, false, true>), dim3(cgrid), b256, 0, stream,
                       x0, W0, (const float*)nullptr, bins, binCur, srcSorted, x1);
    // conv1: x2 = relu(x1 @ root1 + aggr(x1))
    hipLaunchKernelGGL((conv_kernel<128, true, true>), dim3(cgrid), b256, 0, stream,
                       x1, W1, root1, bins, binCur, srcSorted, x2);
    // conv2: final = x2 @ root2 + aggr(x2)  (no relu)
    hipLaunchKernelGGL((conv_kernel<64, true, false>), dim3(cgrid), b256, 0, stream,
                       x2, W2, root2, bins, binCur, srcSorted, out_final);
}